// Round 6
// baseline (432.388 us; speedup 1.0000x reference)
//
#include <hip/hip_runtime.h>
#include <hip/hip_cooperative_groups.h>

namespace cg = cooperative_groups;

#define D 128
#define HDIM 256
#define NB 8            // batch size (fixed by setup_inputs)
#define EPB 64          // entities per tile in score phase
#define NSHARD 8        // topk shards per row
#define CPS 16          // candidates per shard
#define NCAND (NSHARD * CPS)   // 128 candidates per row
#define RCPB 4          // candidates per rescore block

typedef short bf16x8 __attribute__((ext_vector_type(8)));
typedef float f32x4 __attribute__((ext_vector_type(4)));

__device__ __forceinline__ unsigned short f2bf(float x) {
    unsigned u = __float_as_uint(x);
    unsigned r = u + 0x7FFF + ((u >> 16) & 1);   // RNE (finite data)
    return (unsigned short)(r >> 16);
}
__device__ __forceinline__ bf16x8 pack_bf8(float4 u, float4 v) {
    union { bf16x8 v8; unsigned short s[8]; } r;
    r.s[0] = f2bf(u.x); r.s[1] = f2bf(u.y); r.s[2] = f2bf(u.z); r.s[3] = f2bf(u.w);
    r.s[4] = f2bf(v.x); r.s[5] = f2bf(v.y); r.s[6] = f2bf(v.z); r.s[7] = f2bf(v.w);
    return r.v8;
}

// key = (ordered_float << 32) | (0xFFFFFFFF - idx): max == (max val, min idx)
__device__ __forceinline__ unsigned long long sk_encode(float v, int idx) {
    unsigned u = __float_as_uint(v);
    u = (u & 0x80000000u) ? ~u : (u | 0x80000000u);
    return ((unsigned long long)u << 32) | (unsigned)(0xFFFFFFFFu - (unsigned)idx);
}
__device__ __forceinline__ float sk_val(unsigned long long key) {
    const unsigned u = (unsigned)(key >> 32);
    return (u & 0x80000000u) ? __uint_as_float(u & 0x7FFFFFFFu) : __uint_as_float(~u);
}
__device__ __forceinline__ int sk_idx(unsigned long long key) {
    return (int)(0xFFFFFFFFu - (unsigned)(key & 0xFFFFFFFFu));
}
__device__ __forceinline__ unsigned long long wave_max64(unsigned long long m) {
#pragma unroll
    for (int s = 32; s > 0; s >>= 1) {
        const unsigned long long o = __shfl_xor(m, s, 64);
        if (o > m) m = o;
    }
    return m;
}

// ===========================================================================
// Shared device bodies (used by both fused phases and fallback kernels)
// ===========================================================================
__device__ __forceinline__ void prep_body(int w, int tid,
        const int* head, const int* relation, const float* ent_emb,
        const float* rel_emb, const float* W1, const float* b1,
        float* ph_part, unsigned short* w1tt) {
    if (w < 32) {
        const int q = w >> 3, b = w & 7;           // q = K-chunk, b = row
        const int d0 = q * 32;
        const long hidx = head[b];
        const long ridx = relation[b];
        const float* hrow = ent_emb + hidx * D;
        const float* rrow = rel_emb + ridx * D;
        float acc = (q == 0) ? b1[tid] : 0.f;
#pragma unroll 8
        for (int d = d0; d < d0 + 32; ++d)
            acc += hrow[d] * W1[d * HDIM + tid];
#pragma unroll 8
        for (int d = d0; d < d0 + 32; ++d)
            acc += rrow[d] * W1[(D + d) * HDIM + tid];
        ph_part[(q * NB + b) * HDIM + tid] = acc;
    } else {
        const int k0 = (w - 32) * 4;               // 32 work items x 4 k-cols
        const float* w1t = W1 + 2 * D * HDIM;
        unsigned short pk[4];
#pragma unroll
        for (int j = 0; j < 4; ++j)
            pk[j] = f2bf(w1t[(k0 + j) * HDIM + tid]);
        *(ushort4*)(w1tt + tid * D + k0) = make_ushort4(pk[0], pk[1], pk[2], pk[3]);
    }
}

// one 64-entity tile of the MFMA score phase; phT/w2L already staged
__device__ __forceinline__ void score_tile(int base_e, int lane, int wave,
        const float* ent_emb, const unsigned short* w1tt,
        const float (*phT)[NB], const float* w2L, float* scores, int E) {
    const int lm = lane & 15;
    const int q = lane >> 4;
    const int m0 = wave * 16;
    const int erow = base_e + m0 + lm;
    const float* arow = ent_emb + (size_t)min(erow, E - 1) * D;
    bf16x8 aF[4];
#pragma unroll
    for (int kk = 0; kk < 4; ++kk) {
        const float4 u = *(const float4*)(arow + kk * 32 + q * 8);
        const float4 v = *(const float4*)(arow + kk * 32 + q * 8 + 4);
        aF[kk] = pack_bf8(u, v);
    }

    float spart[NB * 4];
#pragma unroll
    for (int i = 0; i < NB * 4; ++i) spart[i] = 0.f;

#pragma unroll
    for (int p = 0; p < 2; ++p) {
#pragma unroll
        for (int nt = 0; nt < 8; ++nt) {
            const int h = p * 128 + nt * 16 + lm;
            const unsigned short* wrow = w1tt + (size_t)h * D + q * 8;
            f32x4 acc = (f32x4){0.f, 0.f, 0.f, 0.f};
#pragma unroll
            for (int kk = 0; kk < 4; ++kk) {
                const bf16x8 bF = *(const bf16x8*)(wrow + kk * 32);
                acc = __builtin_amdgcn_mfma_f32_16x16x32_bf16(aF[kk], bF, acc, 0, 0, 0);
            }
            const float w2v = w2L[h];
            const float4 p0 = *(const float4*)(&phT[h][0]);
            const float4 p1 = *(const float4*)(&phT[h][4]);
            const float phv[8] = {p0.x, p0.y, p0.z, p0.w, p1.x, p1.y, p1.z, p1.w};
#pragma unroll
            for (int b = 0; b < NB; ++b)
#pragma unroll
                for (int r = 0; r < 4; ++r)
                    spart[b * 4 + r] += fmaxf(phv[b] + acc[r], 0.f) * w2v;
        }
    }

#pragma unroll
    for (int m = 1; m <= 8; m <<= 1) {
#pragma unroll
        for (int i = 0; i < NB * 4; ++i)
            spart[i] += __shfl_xor(spart[i], m, 64);
    }
    if (lm == 0) {
#pragma unroll
        for (int r = 0; r < 4; ++r) {
            const int e = base_e + m0 + q * 4 + r;
            if (e < E) {
#pragma unroll
                for (int b = 0; b < NB; ++b)
                    scores[(size_t)b * E + e] = spart[b * 4 + r];
            }
        }
    }
}

__device__ __forceinline__ void topk_shard_body(int w, int tid, int lane, int wave,
        const float* scores, int E, unsigned long long* cand,
        unsigned long long* cl /* shared[64] */) {
    const int b = w >> 3;
    const int s = w & 7;
    const int shard = (E + NSHARD - 1) / NSHARD;
    const int start = s * shard;
    const int end = min(E, start + shard);
    const float* row = scores + (size_t)b * E;

    unsigned long long keys[CPS];
#pragma unroll
    for (int i = 0; i < CPS; ++i) keys[i] = 0ull;

    for (int e = start + tid; e < end; e += 256) {
        unsigned long long key = sk_encode(row[e], e);
        if (key > keys[CPS - 1]) {
#pragma unroll
            for (int j = 0; j < CPS; ++j) {
                const bool gt = key > keys[j];
                const unsigned long long mx = gt ? key : keys[j];
                key = gt ? keys[j] : key;
                keys[j] = mx;
            }
        }
    }

    for (int r = 0; r < CPS; ++r) {
        const unsigned long long m = wave_max64(keys[0]);
        if (keys[0] == m) {
#pragma unroll
            for (int j = 0; j < CPS - 1; ++j) keys[j] = keys[j + 1];
            keys[CPS - 1] = 0ull;
        }
        if (lane == 0) cl[wave * CPS + r] = m;
    }
    __syncthreads();
    if (wave == 0) {
        unsigned long long v = cl[lane];          // exactly 64 candidates
        for (int r = 0; r < CPS; ++r) {
            const unsigned long long m = wave_max64(v);
            if (v == m) v = 0ull;
            if (lane == 0) cand[(size_t)(b * NSHARD + s) * CPS + r] = m;
        }
    }
}

__device__ __forceinline__ void rescore_body(int w, int tid, int lane, int wave,
        const unsigned long long* cand, const float* ent_emb, const float* W1,
        const float* ph_part, const float* W2, const float* b2, float* exact,
        float (*entR)[D], int* eIdx, float (*redR)[RCPB]) {
    const int b = w >> 5;
    const int cgp = w & 31;
    if (tid < RCPB)
        eIdx[tid] = sk_idx(cand[(size_t)b * NCAND + cgp * RCPB + tid]);
    __syncthreads();
    if (tid < RCPB * (D / 4)) {
        const int row = tid >> 5, c4 = (tid & 31) * 4;
        *(float4*)(&entR[row][c4]) =
            *(const float4*)(ent_emb + (size_t)eIdx[row] * D + c4);
    }
    __syncthreads();

    const float* w1t = W1 + 2 * D * HDIM;
    float acc[RCPB] = {0.f, 0.f, 0.f, 0.f};
#pragma unroll 8
    for (int d = 0; d < D; ++d) {
        const float wv = w1t[d * HDIM + tid];
#pragma unroll
        for (int c = 0; c < RCPB; ++c) acc[c] += entR[c][d] * wv;
    }
    const float phv = ph_part[(0 * NB + b) * HDIM + tid]
                    + ph_part[(1 * NB + b) * HDIM + tid]
                    + ph_part[(2 * NB + b) * HDIM + tid]
                    + ph_part[(3 * NB + b) * HDIM + tid];
    const float w2v = W2[tid];
    float s[RCPB];
#pragma unroll
    for (int c = 0; c < RCPB; ++c) s[c] = fmaxf(acc[c] + phv, 0.f) * w2v;

#pragma unroll
    for (int m = 1; m <= 32; m <<= 1)
#pragma unroll
        for (int c = 0; c < RCPB; ++c) s[c] += __shfl_xor(s[c], m, 64);

    if (lane == 0)
#pragma unroll
        for (int c = 0; c < RCPB; ++c) redR[wave][c] = s[c];
    __syncthreads();
    if (tid < RCPB)
        exact[(size_t)b * NCAND + cgp * RCPB + tid] =
            redR[0][tid] + redR[1][tid] + redR[2][tid] + redR[3][tid] + b2[0];
}

__device__ __forceinline__ void final_body(int wave, int lane,
        const unsigned long long* cand, const float* exact, int k, float* out) {
    for (int b = wave; b < NB; b += 4) {
        unsigned long long k0, k1;
        {
            const int c0 = lane, c1 = lane + 64;
            const unsigned long long a = sk_encode(exact[b * NCAND + c0],
                                                   sk_idx(cand[b * NCAND + c0]));
            const unsigned long long bb = sk_encode(exact[b * NCAND + c1],
                                                    sk_idx(cand[b * NCAND + c1]));
            k0 = a > bb ? a : bb;
            k1 = a > bb ? bb : a;
        }
        for (int r = 0; r < k; ++r) {
            const unsigned long long m = wave_max64(k0);
            if (k0 == m) { k0 = k1; k1 = 0ull; }
            if (lane == 0) {
                out[b * k + r] = (float)sk_idx(m);
                out[NB * k + b * k + r] = sk_val(m);
            }
        }
    }
}

// ===========================================================================
// Cooperative fused kernel: 5 phases, grid-stride, works for any grid >= 64.
// ===========================================================================
__global__ __launch_bounds__(256, 2) void fused_kernel(
        const int* __restrict__ head, const int* __restrict__ relation,
        const float* __restrict__ ent_emb, const float* __restrict__ rel_emb,
        const float* __restrict__ W1, const float* __restrict__ b1,
        const float* __restrict__ W2, const float* __restrict__ b2,
        unsigned long long* __restrict__ cand, float* __restrict__ ph_part,
        unsigned short* __restrict__ w1tt, float* __restrict__ exact,
        float* __restrict__ scores, float* __restrict__ out,
        int E, int k) {
    cg::grid_group grid = cg::this_grid();
    const int bid = blockIdx.x;
    const int tid = threadIdx.x;
    const int lane = tid & 63;
    const int wave = tid >> 6;

    __shared__ float phT[HDIM][NB];                 // 8 KB
    __shared__ float w2L[HDIM];                     // 1 KB
    __shared__ unsigned long long cl[4 * CPS];      // 512 B
    __shared__ float entR[RCPB][D];                 // 2 KB
    __shared__ int eIdx[RCPB];
    __shared__ float redR[4][RCPB];

    // ===== Phase A: prep =====
    for (int w = bid; w < 64; w += gridDim.x)
        prep_body(w, tid, head, relation, ent_emb, rel_emb, W1, b1, ph_part, w1tt);
    __threadfence();
    grid.sync();

    // ===== Phase B: MFMA score =====
    {
        w2L[tid] = W2[tid];
#pragma unroll
        for (int b = 0; b < NB; ++b)
            phT[tid][b] = ph_part[(0 * NB + b) * HDIM + tid]
                        + ph_part[(1 * NB + b) * HDIM + tid]
                        + ph_part[(2 * NB + b) * HDIM + tid]
                        + ph_part[(3 * NB + b) * HDIM + tid];
        __syncthreads();
        const int ntile = (E + EPB - 1) / EPB;
        for (int tile = bid; tile < ntile; tile += gridDim.x)
            score_tile(tile * EPB, lane, wave, ent_emb, w1tt, phT, w2L, scores, E);
    }
    __threadfence();
    grid.sync();

    // ===== Phase C: shard top-16 =====
    for (int w = bid; w < NB * NSHARD; w += gridDim.x) {
        topk_shard_body(w, tid, lane, wave, scores, E, cand, cl);
        __syncthreads();
    }
    __threadfence();
    grid.sync();

    // ===== Phase D: exact fp32 rescore =====
    for (int w = bid; w < NB * (NCAND / RCPB); w += gridDim.x) {
        rescore_body(w, tid, lane, wave, cand, ent_emb, W1, ph_part, W2, b2,
                     exact, entR, eIdx, redR);
        __syncthreads();
    }
    __threadfence();
    grid.sync();

    // ===== Phase E: final top-k =====
    if (bid == 0)
        final_body(wave, lane, cand, exact, k, out);
}

// ===========================================================================
// Fallback pipeline (R4-equivalent, known-good) — used if cooperative launch
// is unavailable/rejected. Same ws layout, same bodies.
// ===========================================================================
__global__ __launch_bounds__(HDIM) void prep_kernel_fb(
        const int* __restrict__ head, const int* __restrict__ relation,
        const float* __restrict__ ent_emb, const float* __restrict__ rel_emb,
        const float* __restrict__ W1, const float* __restrict__ b1,
        float* __restrict__ ph_part, unsigned short* __restrict__ w1tt) {
    prep_body(blockIdx.x, threadIdx.x, head, relation, ent_emb, rel_emb,
              W1, b1, ph_part, w1tt);
}

__global__ __launch_bounds__(256) void score_kernel_fb(
        const float* __restrict__ ent_emb, const unsigned short* __restrict__ w1tt,
        const float* __restrict__ ph_part, const float* __restrict__ W2,
        float* __restrict__ scores, int E) {
    __shared__ float phT[HDIM][NB];
    __shared__ float w2L[HDIM];
    const int tid = threadIdx.x;
    w2L[tid] = W2[tid];
#pragma unroll
    for (int b = 0; b < NB; ++b)
        phT[tid][b] = ph_part[(0 * NB + b) * HDIM + tid]
                    + ph_part[(1 * NB + b) * HDIM + tid]
                    + ph_part[(2 * NB + b) * HDIM + tid]
                    + ph_part[(3 * NB + b) * HDIM + tid];
    __syncthreads();
    score_tile(blockIdx.x * EPB, tid & 63, tid >> 6, ent_emb, w1tt, phT, w2L,
               scores, E);
}

__global__ __launch_bounds__(256) void topk_shard_kernel_fb(
        const float* __restrict__ scores, int E,
        unsigned long long* __restrict__ cand) {
    __shared__ unsigned long long cl[4 * CPS];
    const int tid = threadIdx.x;
    topk_shard_body(blockIdx.x, tid, tid & 63, tid >> 6, scores, E, cand, cl);
}

__global__ __launch_bounds__(HDIM) void rescore_kernel_fb(
        const unsigned long long* __restrict__ cand,
        const float* __restrict__ ent_emb, const float* __restrict__ W1,
        const float* __restrict__ ph_part, const float* __restrict__ W2,
        const float* __restrict__ b2, float* __restrict__ exact) {
    __shared__ float entR[RCPB][D];
    __shared__ int eIdx[RCPB];
    __shared__ float redR[4][RCPB];
    const int tid = threadIdx.x;
    rescore_body(blockIdx.x, tid, tid & 63, tid >> 6, cand, ent_emb, W1,
                 ph_part, W2, b2, exact, entR, eIdx, redR);
}

__global__ __launch_bounds__(256) void final_kernel_fb(
        const unsigned long long* __restrict__ cand,
        const float* __restrict__ exact, int k, float* __restrict__ out) {
    final_body(threadIdx.x >> 6, threadIdx.x & 63, cand, exact, k, out);
}

// ===========================================================================
extern "C" void kernel_launch(void* const* d_in, const int* in_sizes, int n_in,
                              void* d_out, int out_size, void* d_ws, size_t ws_size,
                              hipStream_t stream) {
    const int*   head     = (const int*)d_in[0];
    const int*   relation = (const int*)d_in[1];
    const float* ent_emb  = (const float*)d_in[3];
    const float* rel_emb  = (const float*)d_in[4];
    const float* W1       = (const float*)d_in[5];
    const float* b1       = (const float*)d_in[6];
    const float* W2       = (const float*)d_in[7];
    const float* b2       = (const float*)d_in[8];

    const int B = in_sizes[0];          // 8
    int E = in_sizes[3] / D;            // 50000
    int k = out_size / (2 * B);         // 10
    if (k > CPS) k = CPS;

    char* ws = (char*)d_ws;
    unsigned long long* cand  = (unsigned long long*)ws;            //   8 KB
    float*          ph_part   = (float*)(ws + 8192);                //  32 KB
    unsigned short* w1tt      = (unsigned short*)(ws + 40960);      //  64 KB
    float*          exact     = (float*)(ws + 106496);              //   4 KB
    float*          scores    = (float*)(ws + 110592);              // 1.6 MB
    float*          out       = (float*)d_out;

    const int ntile = (E + EPB - 1) / EPB;

    // --- capture-safe host queries (no stream interaction, deterministic) ---
    int dev = 0;
    (void)hipGetDevice(&dev);
    int coop = 0;
    (void)hipDeviceGetAttribute(&coop, hipDeviceAttributeCooperativeLaunch, dev);
    int num_cu = 0;
    (void)hipDeviceGetAttribute(&num_cu, hipDeviceAttributeMultiprocessorCount, dev);
    if (num_cu <= 0) num_cu = 256;
    int per_cu = 0;
    if (coop) {
        if (hipOccupancyMaxActiveBlocksPerMultiprocessor(
                &per_cu, fused_kernel, 256, 0) != hipSuccess)
            per_cu = 0;
    }
    const long max_cores = (long)per_cu * num_cu;

    bool launched = false;
    if (coop && max_cores >= 64) {
        int grid = (int)(max_cores < 512 ? max_cores : 512);
        if (grid > ntile && grid > 256) grid = (ntile > 256 ? ntile : 256);
        void* args[] = {
            (void*)&head, (void*)&relation, (void*)&ent_emb, (void*)&rel_emb,
            (void*)&W1, (void*)&b1, (void*)&W2, (void*)&b2,
            (void*)&cand, (void*)&ph_part, (void*)&w1tt, (void*)&exact,
            (void*)&scores, (void*)&out, (void*)&E, (void*)&k
        };
        if (hipLaunchCooperativeKernel((void*)fused_kernel, dim3(grid), dim3(256),
                                       args, 0, stream) == hipSuccess)
            launched = true;
    }

    if (!launched) {   // fallback: 5-dispatch pipeline (R4 parity)
        prep_kernel_fb<<<64, HDIM, 0, stream>>>(head, relation, ent_emb, rel_emb,
                                                W1, b1, ph_part, w1tt);
        score_kernel_fb<<<ntile, 256, 0, stream>>>(ent_emb, w1tt, ph_part, W2,
                                                   scores, E);
        topk_shard_kernel_fb<<<NB * NSHARD, 256, 0, stream>>>(scores, E, cand);
        rescore_kernel_fb<<<NB * (NCAND / RCPB), HDIM, 0, stream>>>(
            cand, ent_emb, W1, ph_part, W2, b2, exact);
        final_kernel_fb<<<1, 256, 0, stream>>>(cand, exact, k, out);
    }
}

// Round 7
// 174.146 us; speedup vs baseline: 2.4829x; 2.4829x over previous
//
#include <hip/hip_runtime.h>

#define D 128
#define HDIM 256
#define NB 8            // batch size (fixed by setup_inputs)
#define EPB 64          // entities per tile in score kernel
#define NSHARD 8        // topk shards per row
#define CPS 16          // candidates per shard
#define NCAND (NSHARD * CPS)   // 128 candidates per row

typedef short bf16x8 __attribute__((ext_vector_type(8)));
typedef float f32x4 __attribute__((ext_vector_type(4)));

__device__ __forceinline__ unsigned short f2bf(float x) {
    unsigned u = __float_as_uint(x);
    unsigned r = u + 0x7FFF + ((u >> 16) & 1);   // RNE (finite data)
    return (unsigned short)(r >> 16);
}
__device__ __forceinline__ bf16x8 pack_bf8(float4 u, float4 v) {
    union { bf16x8 v8; unsigned short s[8]; } r;
    r.s[0] = f2bf(u.x); r.s[1] = f2bf(u.y); r.s[2] = f2bf(u.z); r.s[3] = f2bf(u.w);
    r.s[4] = f2bf(v.x); r.s[5] = f2bf(v.y); r.s[6] = f2bf(v.z); r.s[7] = f2bf(v.w);
    return r.v8;
}

// key = (ordered_float << 32) | (0xFFFFFFFF - idx): max == (max val, min idx)
__device__ __forceinline__ unsigned long long sk_encode(float v, int idx) {
    unsigned u = __float_as_uint(v);
    u = (u & 0x80000000u) ? ~u : (u | 0x80000000u);
    return ((unsigned long long)u << 32) | (unsigned)(0xFFFFFFFFu - (unsigned)idx);
}
__device__ __forceinline__ float sk_val(unsigned long long key) {
    const unsigned u = (unsigned)(key >> 32);
    return (u & 0x80000000u) ? __uint_as_float(u & 0x7FFFFFFFu) : __uint_as_float(~u);
}
__device__ __forceinline__ int sk_idx(unsigned long long key) {
    return (int)(0xFFFFFFFFu - (unsigned)(key & 0xFFFFFFFFu));
}
__device__ __forceinline__ unsigned long long wave_max64(unsigned long long m) {
#pragma unroll
    for (int s = 32; s > 0; s >>= 1) {
        const unsigned long long o = __shfl_xor(m, s, 64);
        if (o > m) m = o;
    }
    return m;
}

// ---------------------------------------------------------------------------
// K1: 64 blocks. blocks 0..31: ph partials (4 K-chunks x 8 rows);
//     blocks 32..63: w1tt = bf16(W1t^T), 4 k-cols per block.
// ---------------------------------------------------------------------------
__global__ __launch_bounds__(HDIM) void prep_kernel(
        const int* __restrict__ head, const int* __restrict__ relation,
        const float* __restrict__ ent_emb, const float* __restrict__ rel_emb,
        const float* __restrict__ W1, const float* __restrict__ b1,
        float* __restrict__ ph_part, unsigned short* __restrict__ w1tt) {
    const int w = blockIdx.x;
    const int tid = threadIdx.x;
    if (w < 32) {
        const int q = w >> 3, b = w & 7;           // q = K-chunk, b = row
        const int d0 = q * 32;
        const long hidx = head[b];
        const long ridx = relation[b];
        const float* hrow = ent_emb + hidx * D;
        const float* rrow = rel_emb + ridx * D;
        float acc = (q == 0) ? b1[tid] : 0.f;
#pragma unroll 8
        for (int d = d0; d < d0 + 32; ++d)
            acc += hrow[d] * W1[d * HDIM + tid];
#pragma unroll 8
        for (int d = d0; d < d0 + 32; ++d)
            acc += rrow[d] * W1[(D + d) * HDIM + tid];
        ph_part[(q * NB + b) * HDIM + tid] = acc;
    } else {
        const int k0 = (w - 32) * 4;
        const float* w1t = W1 + 2 * D * HDIM;
        unsigned short pk[4];
#pragma unroll
        for (int j = 0; j < 4; ++j)
            pk[j] = f2bf(w1t[(k0 + j) * HDIM + tid]);   // coalesced across tid
        *(ushort4*)(w1tt + tid * D + k0) = make_ushort4(pk[0], pk[1], pk[2], pk[3]);
    }
}

// ---------------------------------------------------------------------------
// K2: MFMA score, no staging LDS (R4-proven). 64 entities x 256 cols, K=128.
// ---------------------------------------------------------------------------
__global__ __launch_bounds__(256) void score_kernel(
        const float* __restrict__ ent_emb, const unsigned short* __restrict__ w1tt,
        const float* __restrict__ ph_part, const float* __restrict__ W2,
        float* __restrict__ scores, int E) {
    __shared__ float phT[HDIM][NB];   // [h][b], 8 KB
    __shared__ float w2L[HDIM];       // 1 KB

    const int tid = threadIdx.x;
    const int lane = tid & 63;
    const int wave = tid >> 6;
    const int lm = lane & 15;
    const int q = lane >> 4;
    const int base_e = blockIdx.x * EPB;
    const int m0 = wave * 16;

    w2L[tid] = W2[tid];
#pragma unroll
    for (int b = 0; b < NB; ++b)
        phT[tid][b] = ph_part[(0 * NB + b) * HDIM + tid]
                    + ph_part[(1 * NB + b) * HDIM + tid]
                    + ph_part[(2 * NB + b) * HDIM + tid]
                    + ph_part[(3 * NB + b) * HDIM + tid];

    const int erow = base_e + m0 + lm;
    const float* arow = ent_emb + (size_t)min(erow, E - 1) * D;
    bf16x8 aF[4];
#pragma unroll
    for (int kk = 0; kk < 4; ++kk) {
        const float4 u = *(const float4*)(arow + kk * 32 + q * 8);
        const float4 v = *(const float4*)(arow + kk * 32 + q * 8 + 4);
        aF[kk] = pack_bf8(u, v);
    }
    __syncthreads();

    float spart[NB * 4];
#pragma unroll
    for (int i = 0; i < NB * 4; ++i) spart[i] = 0.f;

#pragma unroll
    for (int p = 0; p < 2; ++p) {
#pragma unroll
        for (int nt = 0; nt < 8; ++nt) {
            const int h = p * 128 + nt * 16 + lm;
            const unsigned short* wrow = w1tt + (size_t)h * D + q * 8;
            f32x4 acc = (f32x4){0.f, 0.f, 0.f, 0.f};
#pragma unroll
            for (int kk = 0; kk < 4; ++kk) {
                const bf16x8 bF = *(const bf16x8*)(wrow + kk * 32);
                acc = __builtin_amdgcn_mfma_f32_16x16x32_bf16(aF[kk], bF, acc, 0, 0, 0);
            }
            const float w2v = w2L[h];
            const float4 p0 = *(const float4*)(&phT[h][0]);
            const float4 p1 = *(const float4*)(&phT[h][4]);
            const float phv[8] = {p0.x, p0.y, p0.z, p0.w, p1.x, p1.y, p1.z, p1.w};
#pragma unroll
            for (int b = 0; b < NB; ++b)
#pragma unroll
                for (int r = 0; r < 4; ++r)
                    spart[b * 4 + r] += fmaxf(phv[b] + acc[r], 0.f) * w2v;
        }
    }

#pragma unroll
    for (int m = 1; m <= 8; m <<= 1) {
#pragma unroll
        for (int i = 0; i < NB * 4; ++i)
            spart[i] += __shfl_xor(spart[i], m, 64);
    }
    if (lm == 0) {
#pragma unroll
        for (int r = 0; r < 4; ++r) {
            const int e = base_e + m0 + q * 4 + r;
            if (e < E) {
#pragma unroll
                for (int b = 0; b < NB; ++b)
                    scores[(size_t)b * E + e] = spart[b * 4 + r];
            }
        }
    }
}

// ---------------------------------------------------------------------------
// K3: fused shard top-16 + exact fp32 rescore. 64 blocks = 8 rows x 8 shards.
// Phase 1: per-block top-16 over its shard (bf16-approx scores).
// Phase 2: rescore those 16 candidates exactly in-block; write exact keys.
// Shards disjoint -> candidate indices unique; 16/shard margin makes the
// bf16->fp32 candidate superset safe for k=10.
// ---------------------------------------------------------------------------
__global__ __launch_bounds__(256) void topk_rescore_kernel(
        const float* __restrict__ scores, int E,
        const float* __restrict__ ent_emb, const float* __restrict__ W1,
        const float* __restrict__ ph_part, const float* __restrict__ W2,
        const float* __restrict__ b2,
        unsigned long long* __restrict__ cand_exact) {
    const int b = blockIdx.x >> 3;
    const int s = blockIdx.x & 7;
    const int tid = threadIdx.x;
    const int lane = tid & 63;
    const int wave = tid >> 6;

    __shared__ unsigned long long cl[4 * CPS];     // per-wave winners
    __shared__ unsigned long long candk[CPS];      // block's 16 approx keys
    __shared__ int eIdxs[CPS];
    __shared__ float entR[CPS][D];                 // 8 KB
    __shared__ float red[4][CPS];

    // ---- Phase 1: shard scan ----
    {
        const int shard = (E + NSHARD - 1) / NSHARD;
        const int start = s * shard;
        const int end = min(E, start + shard);
        const float* row = scores + (size_t)b * E;

        unsigned long long keys[CPS];
#pragma unroll
        for (int i = 0; i < CPS; ++i) keys[i] = 0ull;

        for (int e = start + tid; e < end; e += 256) {
            unsigned long long key = sk_encode(row[e], e);
            if (key > keys[CPS - 1]) {
#pragma unroll
                for (int j = 0; j < CPS; ++j) {
                    const bool gt = key > keys[j];
                    const unsigned long long mx = gt ? key : keys[j];
                    key = gt ? keys[j] : key;
                    keys[j] = mx;
                }
            }
        }
        for (int r = 0; r < CPS; ++r) {
            const unsigned long long m = wave_max64(keys[0]);
            if (keys[0] == m) {
#pragma unroll
                for (int j = 0; j < CPS - 1; ++j) keys[j] = keys[j + 1];
                keys[CPS - 1] = 0ull;
            }
            if (lane == 0) cl[wave * CPS + r] = m;
        }
        __syncthreads();
        if (wave == 0) {
            unsigned long long v = cl[lane];       // 64 candidates
            for (int r = 0; r < CPS; ++r) {
                const unsigned long long m = wave_max64(v);
                if (v == m) v = 0ull;
                if (lane == 0) candk[r] = m;
            }
        }
        __syncthreads();
    }

    // ---- Phase 2: exact rescore of the 16 candidates ----
    if (tid < CPS) eIdxs[tid] = sk_idx(candk[tid]);
    __syncthreads();
    for (int t = tid; t < CPS * (D / 4); t += 256) {
        const int row = t >> 5, c4 = (t & 31) * 4;
        *(float4*)(&entR[row][c4]) =
            *(const float4*)(ent_emb + (size_t)eIdxs[row] * D + c4);
    }
    __syncthreads();

    const float* w1t = W1 + 2 * D * HDIM;          // thread owns h = tid
    float acc[CPS];
#pragma unroll
    for (int c = 0; c < CPS; ++c) acc[c] = 0.f;
    for (int d0 = 0; d0 < D; d0 += 4) {
        float w[4];
#pragma unroll
        for (int j = 0; j < 4; ++j) w[j] = w1t[(d0 + j) * HDIM + tid];  // coalesced
#pragma unroll
        for (int c = 0; c < CPS; ++c) {
            const float4 f = *(const float4*)(&entR[c][d0]);            // broadcast
            acc[c] += f.x * w[0] + f.y * w[1] + f.z * w[2] + f.w * w[3];
        }
    }
    const float phv = ph_part[(0 * NB + b) * HDIM + tid]
                    + ph_part[(1 * NB + b) * HDIM + tid]
                    + ph_part[(2 * NB + b) * HDIM + tid]
                    + ph_part[(3 * NB + b) * HDIM + tid];
    const float w2v = W2[tid];
    float sc[CPS];
#pragma unroll
    for (int c = 0; c < CPS; ++c) sc[c] = fmaxf(acc[c] + phv, 0.f) * w2v;

#pragma unroll
    for (int m = 1; m <= 32; m <<= 1)
#pragma unroll
        for (int c = 0; c < CPS; ++c) sc[c] += __shfl_xor(sc[c], m, 64);
    if (lane == 0)
#pragma unroll
        for (int c = 0; c < CPS; ++c) red[wave][c] = sc[c];
    __syncthreads();
    if (tid < CPS) {
        const float v = red[0][tid] + red[1][tid] + red[2][tid] + red[3][tid] + b2[0];
        cand_exact[(size_t)(b * NSHARD + s) * CPS + tid] = sk_encode(v, eIdxs[tid]);
    }
}

// ---------------------------------------------------------------------------
// K4: final top-k per row from 128 exactly-scored keys. 1 block, wave = row.
// ---------------------------------------------------------------------------
__global__ __launch_bounds__(256) void final_kernel(
        const unsigned long long* __restrict__ cand_exact, int k,
        float* __restrict__ out) {
    const int lane = threadIdx.x & 63;
    const int wave = threadIdx.x >> 6;
    for (int b = wave; b < NB; b += 4) {
        unsigned long long k0 = cand_exact[(size_t)b * NCAND + lane];
        unsigned long long k1 = cand_exact[(size_t)b * NCAND + 64 + lane];
        if (k1 > k0) { const unsigned long long t = k0; k0 = k1; k1 = t; }
        for (int r = 0; r < k; ++r) {
            const unsigned long long m = wave_max64(k0);
            if (k0 == m) { k0 = k1; k1 = 0ull; }
            if (lane == 0) {
                out[b * k + r] = (float)sk_idx(m);          // indices
                out[NB * k + b * k + r] = sk_val(m);        // scores
            }
        }
    }
}

// ---------------------------------------------------------------------------
extern "C" void kernel_launch(void* const* d_in, const int* in_sizes, int n_in,
                              void* d_out, int out_size, void* d_ws, size_t ws_size,
                              hipStream_t stream) {
    const int*   head     = (const int*)d_in[0];
    const int*   relation = (const int*)d_in[1];
    const float* ent_emb  = (const float*)d_in[3];
    const float* rel_emb  = (const float*)d_in[4];
    const float* W1       = (const float*)d_in[5];
    const float* b1       = (const float*)d_in[6];
    const float* W2       = (const float*)d_in[7];
    const float* b2       = (const float*)d_in[8];

    const int B = in_sizes[0];          // 8
    const int E = in_sizes[3] / D;      // 50000
    int k = out_size / (2 * B);         // 10
    if (k > CPS) k = CPS;

    char* ws = (char*)d_ws;
    unsigned long long* cand_exact = (unsigned long long*)ws;       //   8 KB
    float*          ph_part   = (float*)(ws + 8192);                //  32 KB
    unsigned short* w1tt      = (unsigned short*)(ws + 40960);      //  64 KB
    float*          scores    = (float*)(ws + 106496);              // 1.6 MB
    float*          out       = (float*)d_out;

    const int ntile = (E + EPB - 1) / EPB;

    prep_kernel<<<64, HDIM, 0, stream>>>(head, relation, ent_emb, rel_emb,
                                         W1, b1, ph_part, w1tt);
    score_kernel<<<ntile, 256, 0, stream>>>(ent_emb, w1tt, ph_part, W2, scores, E);
    topk_rescore_kernel<<<NB * NSHARD, 256, 0, stream>>>(
        scores, E, ent_emb, W1, ph_part, W2, b2, cand_exact);
    final_kernel<<<1, 256, 0, stream>>>(cand_exact, k, out);
}